// Round 2
// baseline (1804.001 us; speedup 1.0000x reference)
//
#include <hip/hip_runtime.h>
#include <hip/hip_bf16.h>

// MoE dense layer: out[n,r] = sum_e softmax(x@gw+gb)[n,e] * (x @ W_e + b_e)[n,r]
// N = D_IN = D_OUT = 4096, E = 8.
//
// Fast path (needs ~302MB ws):
//   k1: gate softmax -> gate[4096][8] fp32, fused with x fp32 -> x_bf16
//       (float4 x loads, packed ushort4 stores, shfl wave reduction)
//   k2: expert_w fp32 [32768][4096] -> Bt bf16 [4096][32768]
//       (8B packed LDS writes, XOR-swizzled granules; conflict-free both sides)
//   k3: single GEMM M=4096,N=4096,K=32768 (experts concatenated along K),
//       256x256 tile, 8 waves, BK=32, 4-slot LDS ring, depth-2 prefetch.
//       NEW: per-tile compute split into 2 phases of 16 MFMA each
//       (m201 8-phase shape: ds_read cluster || stage 1 operand || barrier ||
//       lgkmcnt(0) || setprio+16 MFMA || barrier), vmcnt(4) once per tile.

typedef __attribute__((ext_vector_type(8))) short short8;   // 8 bf16 in 4 VGPRs
typedef __attribute__((ext_vector_type(4))) float f32x4;

#define NROWS 4096
#define DIN   4096
#define DOUT  4096
#define NEXP  8
#define KTOT  (NEXP * DIN)   // 32768

// ---------- helpers ----------
__device__ __forceinline__ unsigned short f2b(float f) {
  unsigned int u = __float_as_uint(f);
  u += 0x7FFFu + ((u >> 16) & 1u);   // round-to-nearest-even
  return (unsigned short)(u >> 16);
}

__device__ __forceinline__ void gload_lds16(const unsigned short* g, unsigned short* l) {
  // global -> LDS direct DMA, 16B/lane; LDS dest = wave-uniform base + lane*16.
  __builtin_amdgcn_global_load_lds(
      (const __attribute__((address_space(1))) unsigned int*)(unsigned long long)g,
      (__attribute__((address_space(3))) unsigned int*)(unsigned int)(unsigned long long)l,
      16, 0, 0);
}

// ---------- k1: gate softmax + x->bf16 (fused; one block per row) ----------
__global__ __launch_bounds__(256) void gate_kernel(const float* __restrict__ x,
                                                   const float* __restrict__ gw,
                                                   const float* __restrict__ gb,
                                                   float* __restrict__ g,
                                                   unsigned short* __restrict__ xb) {
  __shared__ float red[4][8];
  const int n = blockIdx.x, t = threadIdx.x;
  const int lane = t & 63, w = t >> 6;
  float a[8] = {0, 0, 0, 0, 0, 0, 0, 0};
  #pragma unroll
  for (int it = 0; it < DIN / 1024; ++it) {            // 4 iters
    const int d = (it * 256 + t) * 4;
    float4 xv = *(const float4*)(x + (size_t)n * DIN + d);
    ushort4 p;
    p.x = f2b(xv.x); p.y = f2b(xv.y); p.z = f2b(xv.z); p.w = f2b(xv.w);
    *(ushort4*)(xb + (size_t)n * DIN + d) = p;
    const float xs[4] = {xv.x, xv.y, xv.z, xv.w};
    #pragma unroll
    for (int q = 0; q < 4; ++q) {
      const float4* gwp = (const float4*)(gw + (size_t)(d + q) * 8);
      float4 w0 = gwp[0], w1 = gwp[1];
      a[0] += xs[q] * w0.x; a[1] += xs[q] * w0.y; a[2] += xs[q] * w0.z; a[3] += xs[q] * w0.w;
      a[4] += xs[q] * w1.x; a[5] += xs[q] * w1.y; a[6] += xs[q] * w1.z; a[7] += xs[q] * w1.w;
    }
  }
  // wave butterfly reduction (64 lanes)
  #pragma unroll
  for (int off = 32; off; off >>= 1)
    #pragma unroll
    for (int e = 0; e < 8; ++e) a[e] += __shfl_xor(a[e], off);
  if (lane == 0)
    #pragma unroll
    for (int e = 0; e < 8; ++e) red[w][e] = a[e];
  __syncthreads();
  if (t == 0) {
    float l[8], m = -1e30f, ssum = 0.f;
    for (int e = 0; e < 8; ++e) {
      l[e] = red[0][e] + red[1][e] + red[2][e] + red[3][e] + gb[e];
      m = fmaxf(m, l[e]);
    }
    for (int e = 0; e < 8; ++e) { l[e] = expf(l[e] - m); ssum += l[e]; }
    for (int e = 0; e < 8; ++e) g[(size_t)n * 8 + e] = l[e] / ssum;
  }
}

// ---------- k2: expert_w [32768][4096] fp32 -> Bt [4096][32768] bf16 ----------
// LDS tile natural [k][r] orientation, 8B-granule XOR swizzle on both sides:
//   write: 16-lane groups (same k) hit a permutation of the 16 granules ->
//          all 32 banks, ds_write_b64 conflict-free.
//   read : transposed scalar u16 gather; swizzle spreads the k-column across
//          banks (<=2-way, which is free on CDNA4).
__global__ __launch_bounds__(256) void transpose_w(const float* __restrict__ W,
                                                   unsigned short* __restrict__ bt) {
  __shared__ unsigned short tile[64 * 64];   // 8KB, [k][granule-swizzled r]
  const int t = threadIdx.x;
  const int k0 = blockIdx.x * 64, r0 = blockIdx.y * 64;
  #pragma unroll
  for (int i = 0; i < 4; ++i) {
    int lin = i * 256 + t;                 // 0..1023
    int kr = lin >> 4;                     // k row 0..63
    int G = lin & 15;                      // r-granule 0..15 (4 shorts = 8B)
    float4 v = *(const float4*)(W + (size_t)(k0 + kr) * 4096 + r0 + G * 4);
    int slot = G ^ (kr & 15) ^ ((kr >> 4) & 3);
    ushort4 p;
    p.x = f2b(v.x); p.y = f2b(v.y); p.z = f2b(v.z); p.w = f2b(v.w);
    *(ushort4*)&tile[kr * 64 + slot * 4] = p;
  }
  __syncthreads();
  #pragma unroll
  for (int i = 0; i < 2; ++i) {
    int lin = i * 256 + t;                 // 0..511
    int rr = lin >> 3;                     // output row (r) 0..63
    int kc = (lin & 7) * 8;                // k chunk
    unsigned short buf[8];
    #pragma unroll
    for (int j = 0; j < 8; ++j) {
      int k = kc + j;
      int slot = (rr >> 2) ^ (k & 15) ^ ((k >> 4) & 3);
      buf[j] = tile[k * 64 + slot * 4 + (rr & 3)];
    }
    *(uint4*)(bt + (size_t)(r0 + rr) * KTOT + k0 + kc) = *(uint4*)buf;
  }
}

// ---------- k3: main GEMM, 256x256 tile, BK=32, 4-slot ring, 2-phase/tile ----
#define BM 256
#define BN 256
#define BKK 32
#define NTILES (KTOT / BKK)       // 1024
#define SLOT_SH 8192              // shorts per slot: 256 rows * 32 k

__global__ __launch_bounds__(512, 2) void gemm_moe(const unsigned short* __restrict__ xb,
                                                   const unsigned short* __restrict__ bt,
                                                   const float* __restrict__ gate,
                                                   const float* __restrict__ eb,
                                                   float* __restrict__ out) {
  __shared__ alignas(16) unsigned short sA[4 * SLOT_SH];   // 64KB
  __shared__ alignas(16) unsigned short sB[4 * SLOT_SH];   // 64KB
  __shared__ float sG[256 * 8];                            // 8KB gate rows
  __shared__ float sBias[8 * 256];                         // 8KB expert_b cols

  const int t = threadIdx.x;
  const int lane = t & 63;
  const int w = t >> 6;            // wave 0..7
  const int wm = w >> 2;           // 0..1  (M half)
  const int wn = w & 3;            // 0..3  (N quarter)

  // XCD-chunked mapping: 256 blocks, 8 XCDs, each XCD = 2 B-panels x 16 M-tiles
  const int bid = blockIdx.x;
  const int wg = (bid & 7) * 32 + (bid >> 3);   // bijective (256 % 8 == 0)
  const int tn = wg >> 4;          // 0..15
  const int tm = wg & 15;          // 0..15
  const int row0 = tm * BM;
  const int col0 = tn * BN;

  // prologue: gate + bias tiles (stable for whole kernel)
  #pragma unroll
  for (int i = 0; i < 4; ++i) {
    int lin = i * 512 + t;         // 0..2047
    sG[lin] = gate[(size_t)row0 * 8 + lin];
    sBias[lin] = eb[(size_t)(lin >> 8) * DOUT + col0 + (lin & 255)];
  }

  const int mrow = lane & 15;
  const int quad = lane >> 4;
  const int rs = (quad ^ ((mrow >> 1) & 3)) * 8;   // swizzled 16B granule (shorts)

  // staging addresses (constant per thread)
  const int srow = w * 16 + (lane >> 2);           // 0..127 (half-tile row)
  const int sg0 = (lane & 3) ^ ((srow >> 1) & 3);
  const int sg1 = (lane & 3) ^ (((srow + 128) >> 1) & 3);

  f32x4 acc[8][4];
  #pragma unroll
  for (int i = 0; i < 8; ++i)
    #pragma unroll
    for (int j = 0; j < 4; ++j) acc[i][j] = (f32x4){0.f, 0.f, 0.f, 0.f};

  auto stageA = [&](int T) {
    const int s = T & 3;
    const int kA = (T * BKK) & (DIN - 1);          // x wraps every expert
    gload_lds16(xb + (size_t)(row0 + srow) * DIN + kA + sg0 * 8,
                &sA[s * SLOT_SH + (w * 64) * 8]);
    gload_lds16(xb + (size_t)(row0 + 128 + srow) * DIN + kA + sg1 * 8,
                &sA[s * SLOT_SH + (512 + w * 64) * 8]);
  };
  auto stageB = [&](int T) {
    const int s = T & 3;
    const int kB = T * BKK;
    gload_lds16(bt + (size_t)(col0 + srow) * KTOT + kB + sg0 * 8,
                &sB[s * SLOT_SH + (w * 64) * 8]);
    gload_lds16(bt + (size_t)(col0 + 128 + srow) * KTOT + kB + sg1 * 8,
                &sB[s * SLOT_SH + (512 + w * 64) * 8]);
  };

  // pipeline prologue: tiles 0,1 fully in flight; wait for tile 0 (newest 4 = tile 1)
  stageA(0); stageB(0);
  stageA(1); stageB(1);
  asm volatile("s_waitcnt vmcnt(4)" ::: "memory");
  __builtin_amdgcn_s_barrier();

  for (int T = 0; T < NTILES; ++T) {
    const int s = T & 3;
    const unsigned short* sAs = &sA[s * SLOT_SH];
    const unsigned short* sBs = &sB[s * SLOT_SH];

    // ---- phase 1: af i0..3 + bf, stage A(T+2), 16 MFMA ----
    short8 af0[4], bf[4];
    #pragma unroll
    for (int i = 0; i < 4; ++i)
      af0[i] = *(const short8*)&sAs[(wm * 128 + i * 16 + mrow) * 32 + rs];
    #pragma unroll
    for (int j = 0; j < 4; ++j)
      bf[j] = *(const short8*)&sBs[(wn * 64 + j * 16 + mrow) * 32 + rs];
    if (T < NTILES - 2) stageA(T + 2);
    __builtin_amdgcn_s_barrier();
    asm volatile("s_waitcnt lgkmcnt(0)" ::: "memory");
    __builtin_amdgcn_s_setprio(1);
    #pragma unroll
    for (int i = 0; i < 4; ++i)
      #pragma unroll
      for (int j = 0; j < 4; ++j)
        acc[i][j] = __builtin_amdgcn_mfma_f32_16x16x32_bf16(af0[i], bf[j], acc[i][j], 0, 0, 0);
    __builtin_amdgcn_s_setprio(0);
    __builtin_amdgcn_s_barrier();

    // ---- phase 2: af i4..7, stage B(T+2), 16 MFMA ----
    short8 af1[4];
    #pragma unroll
    for (int i = 0; i < 4; ++i)
      af1[i] = *(const short8*)&sAs[(wm * 128 + (4 + i) * 16 + mrow) * 32 + rs];
    if (T < NTILES - 2) stageB(T + 2);
    __builtin_amdgcn_s_barrier();
    asm volatile("s_waitcnt lgkmcnt(0)" ::: "memory");
    __builtin_amdgcn_s_setprio(1);
    #pragma unroll
    for (int i = 0; i < 4; ++i)
      #pragma unroll
      for (int j = 0; j < 4; ++j)
        acc[4 + i][j] = __builtin_amdgcn_mfma_f32_16x16x32_bf16(af1[i], bf[j], acc[4 + i][j], 0, 0, 0);
    __builtin_amdgcn_s_setprio(0);

    if (T < NTILES - 1) {
      // counted wait: tile T+1 guaranteed landed, tile T+2 stays in flight
      if (T < NTILES - 2) asm volatile("s_waitcnt vmcnt(4)" ::: "memory");
      else                asm volatile("s_waitcnt vmcnt(0)" ::: "memory");
      __builtin_amdgcn_s_barrier();

      // expert boundary: fold gate weight via in-place rescale (telescoping)
      if ((T & 127) == 127) {
        const int e = T >> 7;
        #pragma unroll
        for (int i = 0; i < 8; ++i) {
          #pragma unroll
          for (int r = 0; r < 4; ++r) {
            const int row_l = wm * 128 + i * 16 + quad * 4 + r;
            const float sc = sG[row_l * 8 + e] / sG[row_l * 8 + e + 1];
            #pragma unroll
            for (int j = 0; j < 4; ++j) acc[i][j][r] *= sc;
          }
        }
      }
    }
  }

  // epilogue: *g7, + sum_e g_e * b_e[col]
  #pragma unroll
  for (int i = 0; i < 8; ++i) {
    #pragma unroll
    for (int r = 0; r < 4; ++r) {
      const int row_l = wm * 128 + i * 16 + quad * 4 + r;
      float gv[8];
      #pragma unroll
      for (int e = 0; e < 8; ++e) gv[e] = sG[row_l * 8 + e];
      #pragma unroll
      for (int j = 0; j < 4; ++j) {
        const int col_l = wn * 64 + j * 16 + mrow;
        float bias = 0.f;
        #pragma unroll
        for (int e = 0; e < 8; ++e) bias += gv[e] * sBias[e * 256 + col_l];
        out[(size_t)(row0 + row_l) * DOUT + col0 + col_l] = acc[i][j][r] * gv[7] + bias;
      }
    }
  }
}

// ---------- fallback: fp32, no workspace ----------
__global__ __launch_bounds__(256) void moe_fallback(const float* __restrict__ x,
                                                    const float* __restrict__ gw,
                                                    const float* __restrict__ gb,
                                                    const float* __restrict__ W,
                                                    const float* __restrict__ eb,
                                                    float* __restrict__ out) {
  __shared__ float sX[64][33];
  __shared__ float sW[32][65];
  __shared__ float sLog[64][8];
  __shared__ float sGate[64][8];
  const int t = threadIdx.x;
  const int r0 = blockIdx.y * 64, c0 = blockIdx.x * 64;

  const int grow = t & 63, epair = t >> 6;
  float lg0 = gb[2 * epair], lg1 = gb[2 * epair + 1];
  for (int d0 = 0; d0 < DIN; d0 += 32) {
    for (int i = 0; i < 8; ++i) {
      int lin = i * 256 + t, rr = lin >> 5, cc = lin & 31;
      sX[rr][cc] = x[(size_t)(r0 + rr) * DIN + d0 + cc];
    }
    __syncthreads();
    for (int dd = 0; dd < 32; ++dd) {
      float xv = sX[grow][dd];
      lg0 += xv * gw[(size_t)(d0 + dd) * 8 + 2 * epair];
      lg1 += xv * gw[(size_t)(d0 + dd) * 8 + 2 * epair + 1];
    }
    __syncthreads();
  }
  sLog[grow][2 * epair] = lg0;
  sLog[grow][2 * epair + 1] = lg1;
  __syncthreads();
  if (t < 64) {
    float m = -1e30f, s = 0.f, ex[8];
    for (int e = 0; e < 8; ++e) m = fmaxf(m, sLog[t][e]);
    for (int e = 0; e < 8; ++e) { ex[e] = expf(sLog[t][e] - m); s += ex[e]; }
    for (int e = 0; e < 8; ++e) sGate[t][e] = ex[e] / s;
  }
  __syncthreads();

  const int tr = t >> 4, tc = t & 15;
  float acc[4][4] = {};
  for (int e = 0; e < NEXP; ++e) {
    float part[4][4] = {};
    for (int d0 = 0; d0 < DIN; d0 += 32) {
      for (int i = 0; i < 8; ++i) {
        int lin = i * 256 + t, rr = lin >> 5, cc = lin & 31;
        sX[rr][cc] = x[(size_t)(r0 + rr) * DIN + d0 + cc];
      }
      for (int i = 0; i < 8; ++i) {
        int lin = i * 256 + t, dd = lin >> 6, cc = lin & 63;
        sW[dd][cc] = W[(size_t)e * DIN * DOUT + (size_t)(d0 + dd) * DOUT + c0 + cc];
      }
      __syncthreads();
      for (int dd = 0; dd < 32; ++dd) {
        float xa[4], wb[4];
        for (int i = 0; i < 4; ++i) xa[i] = sX[tr + 16 * i][dd];
        for (int j = 0; j < 4; ++j) wb[j] = sW[dd][tc + 16 * j];
        for (int i = 0; i < 4; ++i)
          for (int j = 0; j < 4; ++j) part[i][j] += xa[i] * wb[j];
      }
      __syncthreads();
    }
    for (int i = 0; i < 4; ++i) {
      float g = sGate[tr + 16 * i][e];
      for (int j = 0; j < 4; ++j)
        acc[i][j] += g * (part[i][j] + eb[(size_t)e * DOUT + c0 + tc + 16 * j]);
    }
  }
  for (int i = 0; i < 4; ++i)
    for (int j = 0; j < 4; ++j)
      out[(size_t)(r0 + tr + 16 * i) * DOUT + c0 + tc + 16 * j] = acc[i][j];
}

extern "C" void kernel_launch(void* const* d_in, const int* in_sizes, int n_in,
                              void* d_out, int out_size, void* d_ws, size_t ws_size,
                              hipStream_t stream) {
  const float* x  = (const float*)d_in[0];
  const float* gw = (const float*)d_in[1];
  const float* gb = (const float*)d_in[2];
  const float* W  = (const float*)d_in[3];
  const float* eb = (const float*)d_in[4];
  float* out = (float*)d_out;

  const size_t sz_xb = (size_t)NROWS * DIN * 2;          // 32MB
  const size_t sz_bt = (size_t)DOUT * KTOT * 2;          // 256MB
  const size_t sz_g  = (size_t)NROWS * 8 * 4;            // 128KB
  const size_t need = sz_xb + sz_bt + sz_g;

  if (ws_size >= need) {
    unsigned short* xb = (unsigned short*)d_ws;
    unsigned short* bt = (unsigned short*)((char*)d_ws + sz_xb);
    float* gate = (float*)((char*)d_ws + sz_xb + sz_bt);
    gate_kernel<<<NROWS, 256, 0, stream>>>(x, gw, gb, gate, xb);
    transpose_w<<<dim3(KTOT / 64, DOUT / 64), 256, 0, stream>>>(W, bt);
    gemm_moe<<<(NROWS / BM) * (DOUT / BN), 512, 0, stream>>>(xb, bt, gate, eb, out);
  } else {
    moe_fallback<<<dim3(DOUT / 64, NROWS / 64), 256, 0, stream>>>(x, gw, gb, W, eb, out);
  }
}

// Round 3
// 1723.833 us; speedup vs baseline: 1.0465x; 1.0465x over previous
//
#include <hip/hip_runtime.h>
#include <hip/hip_bf16.h>

// MoE dense layer: out[n,r] = sum_e softmax(x@gw+gb)[n,e] * (x @ W_e + b_e)[n,r]
// N = D_IN = D_OUT = 4096, E = 8.
//
// Fast path (needs ~302MB ws):
//   k1: gate softmax -> gate[4096][8] fp32, fused with x fp32 -> x_bf16
//   k2: expert_w fp32 [32768][4096] -> bt2 bf16, K-TILED layout:
//       bt2[T][c][kk], T = k/32, kk = k&31  (c = output column).
//       Writes are 16KB-contiguous streams; reads are 1KB chunks.
//   k3: single GEMM M=4096,N=4096,K=32768, 256x256 tile, 8 waves, BK=32,
//       4-slot LDS ring, depth-2 prefetch, counted vmcnt(4), raw s_barrier,
//       setprio around the 32-MFMA cluster (R1 schedule — R2's 2-phase split
//       regressed and was reverted). stageB now reads one contiguous 16KB
//       span per K-tile thanks to the k-tiled bt2 layout.

typedef __attribute__((ext_vector_type(8))) short short8;   // 8 bf16 in 4 VGPRs
typedef __attribute__((ext_vector_type(4))) float f32x4;

#define NROWS 4096
#define DIN   4096
#define DOUT  4096
#define NEXP  8
#define KTOT  (NEXP * DIN)   // 32768

// ---------- helpers ----------
__device__ __forceinline__ unsigned short f2b(float f) {
  unsigned int u = __float_as_uint(f);
  u += 0x7FFFu + ((u >> 16) & 1u);   // round-to-nearest-even
  return (unsigned short)(u >> 16);
}

__device__ __forceinline__ void gload_lds16(const unsigned short* g, unsigned short* l) {
  // global -> LDS direct DMA, 16B/lane; LDS dest = wave-uniform base + lane*16.
  __builtin_amdgcn_global_load_lds(
      (const __attribute__((address_space(1))) unsigned int*)(unsigned long long)g,
      (__attribute__((address_space(3))) unsigned int*)(unsigned int)(unsigned long long)l,
      16, 0, 0);
}

// ---------- k1: gate softmax + x->bf16 (fused; one block per row) ----------
__global__ __launch_bounds__(256) void gate_kernel(const float* __restrict__ x,
                                                   const float* __restrict__ gw,
                                                   const float* __restrict__ gb,
                                                   float* __restrict__ g,
                                                   unsigned short* __restrict__ xb) {
  __shared__ float red[4][8];
  const int n = blockIdx.x, t = threadIdx.x;
  const int lane = t & 63, w = t >> 6;
  float a[8] = {0, 0, 0, 0, 0, 0, 0, 0};
  #pragma unroll
  for (int it = 0; it < DIN / 1024; ++it) {            // 4 iters
    const int d = (it * 256 + t) * 4;
    float4 xv = *(const float4*)(x + (size_t)n * DIN + d);
    ushort4 p;
    p.x = f2b(xv.x); p.y = f2b(xv.y); p.z = f2b(xv.z); p.w = f2b(xv.w);
    *(ushort4*)(xb + (size_t)n * DIN + d) = p;
    const float xs[4] = {xv.x, xv.y, xv.z, xv.w};
    #pragma unroll
    for (int q = 0; q < 4; ++q) {
      const float4* gwp = (const float4*)(gw + (size_t)(d + q) * 8);
      float4 w0 = gwp[0], w1 = gwp[1];
      a[0] += xs[q] * w0.x; a[1] += xs[q] * w0.y; a[2] += xs[q] * w0.z; a[3] += xs[q] * w0.w;
      a[4] += xs[q] * w1.x; a[5] += xs[q] * w1.y; a[6] += xs[q] * w1.z; a[7] += xs[q] * w1.w;
    }
  }
  // wave butterfly reduction (64 lanes)
  #pragma unroll
  for (int off = 32; off; off >>= 1)
    #pragma unroll
    for (int e = 0; e < 8; ++e) a[e] += __shfl_xor(a[e], off);
  if (lane == 0)
    #pragma unroll
    for (int e = 0; e < 8; ++e) red[w][e] = a[e];
  __syncthreads();
  if (t == 0) {
    float l[8], m = -1e30f, ssum = 0.f;
    for (int e = 0; e < 8; ++e) {
      l[e] = red[0][e] + red[1][e] + red[2][e] + red[3][e] + gb[e];
      m = fmaxf(m, l[e]);
    }
    for (int e = 0; e < 8; ++e) { l[e] = expf(l[e] - m); ssum += l[e]; }
    for (int e = 0; e < 8; ++e) g[(size_t)n * 8 + e] = l[e] / ssum;
  }
}

// ---------- k2: expert_w [32768][4096] fp32 -> bt2 k-tiled bf16 ----------
// bt2[((T*4096)+c)*32 + kk], T=k/32, kk=k&31. Per block: 64 k x 256 r.
// Reads 1KB/row chunks; writes two 16KB contiguous streams. LDS tile [k][r]
// with 8B-granule XOR swizzle (slot = g ^ (k&31)): write conflict-free,
// transposed scalar read <=2-way (free).
__global__ __launch_bounds__(256) void transpose_w(const float* __restrict__ W,
                                                   unsigned short* __restrict__ bt) {
  __shared__ unsigned short tile[64 * 256];   // 32KB
  const int t = threadIdx.x;
  const int k0 = blockIdx.x * 64, r0 = blockIdx.y * 256;
  #pragma unroll
  for (int i = 0; i < 16; ++i) {
    int lin = i * 256 + t;                 // 0..4095
    int kr = lin >> 6;                     // k row 0..63
    int gg = lin & 63;                     // r-granule (4 floats)
    float4 v = *(const float4*)(W + (size_t)(k0 + kr) * 4096 + r0 + gg * 4);
    int slot = gg ^ (kr & 31);             // bijective within [0,64)
    ushort4 p;
    p.x = f2b(v.x); p.y = f2b(v.y); p.z = f2b(v.z); p.w = f2b(v.w);
    *(ushort4*)&tile[kr * 256 + slot * 4] = p;
  }
  __syncthreads();
  #pragma unroll
  for (int i = 0; i < 8; ++i) {
    int lin = i * 256 + t;                 // 0..2047
    int kc = (lin & 3) * 8;                // kk chunk base (8 shorts)
    int c  = (lin >> 2) & 255;             // column within panel
    int Tl = lin >> 10;                    // 0..1 (which 32-k subtile)
    unsigned short buf[8];
    #pragma unroll
    for (int j = 0; j < 8; ++j) {
      int k = Tl * 32 + kc + j;
      int slot = (c >> 2) ^ (k & 31);
      buf[j] = tile[k * 256 + slot * 4 + (c & 3)];
    }
    size_t T = (size_t)(blockIdx.x * 2 + Tl);
    *(uint4*)(bt + (T * 4096 + r0 + c) * 32 + kc) = *(uint4*)buf;
  }
}

// ---------- k3: main GEMM, 256x256 tile, BK=32, 4-slot ring (R1 schedule) ---
#define BM 256
#define BN 256
#define BKK 32
#define NTILES (KTOT / BKK)       // 1024
#define SLOT_SH 8192              // shorts per slot: 256 rows * 32 k

__global__ __launch_bounds__(512, 2) void gemm_moe(const unsigned short* __restrict__ xb,
                                                   const unsigned short* __restrict__ bt,
                                                   const float* __restrict__ gate,
                                                   const float* __restrict__ eb,
                                                   float* __restrict__ out) {
  __shared__ alignas(16) unsigned short sA[4 * SLOT_SH];   // 64KB
  __shared__ alignas(16) unsigned short sB[4 * SLOT_SH];   // 64KB
  __shared__ float sG[256 * 8];                            // 8KB gate rows
  __shared__ float sBias[8 * 256];                         // 8KB expert_b cols

  const int t = threadIdx.x;
  const int lane = t & 63;
  const int w = t >> 6;            // wave 0..7
  const int wm = w >> 2;           // 0..1  (M half)
  const int wn = w & 3;            // 0..3  (N quarter)

  // XCD-chunked mapping: 256 blocks, 8 XCDs, each XCD = 2 B-panels x 16 M-tiles
  const int bid = blockIdx.x;
  const int wg = (bid & 7) * 32 + (bid >> 3);   // bijective (256 % 8 == 0)
  const int tn = wg >> 4;          // 0..15
  const int tm = wg & 15;          // 0..15
  const int row0 = tm * BM;
  const int col0 = tn * BN;

  // prologue: gate + bias tiles (stable for whole kernel)
  #pragma unroll
  for (int i = 0; i < 4; ++i) {
    int lin = i * 512 + t;         // 0..2047
    sG[lin] = gate[(size_t)row0 * 8 + lin];
    sBias[lin] = eb[(size_t)(lin >> 8) * DOUT + col0 + (lin & 255)];
  }

  const int mrow = lane & 15;
  const int quad = lane >> 4;
  const int rs = (quad ^ ((mrow >> 1) & 3)) * 8;   // swizzled 16B granule (shorts)

  // staging addresses (constant per thread)
  const int srow = w * 16 + (lane >> 2);           // 0..127 (half-tile row)
  const int sg0 = (lane & 3) ^ ((srow >> 1) & 3);
  const int sg1 = (lane & 3) ^ (((srow + 128) >> 1) & 3);

  f32x4 acc[8][4];
  #pragma unroll
  for (int i = 0; i < 8; ++i)
    #pragma unroll
    for (int j = 0; j < 4; ++j) acc[i][j] = (f32x4){0.f, 0.f, 0.f, 0.f};

  auto stageA = [&](int T) {
    const int s = T & 3;
    const int kA = (T * BKK) & (DIN - 1);          // x wraps every expert
    gload_lds16(xb + (size_t)(row0 + srow) * DIN + kA + sg0 * 8,
                &sA[s * SLOT_SH + (w * 64) * 8]);
    gload_lds16(xb + (size_t)(row0 + 128 + srow) * DIN + kA + sg1 * 8,
                &sA[s * SLOT_SH + (512 + w * 64) * 8]);
  };
  auto stageB = [&](int T) {
    const int s = T & 3;
    const unsigned short* base = bt + ((size_t)T * 4096 + col0) * 32;  // 16KB span
    gload_lds16(base + (size_t)srow * 32 + sg0 * 8,
                &sB[s * SLOT_SH + (w * 64) * 8]);
    gload_lds16(base + (size_t)(128 + srow) * 32 + sg1 * 8,
                &sB[s * SLOT_SH + (512 + w * 64) * 8]);
  };

  // pipeline prologue: tiles 0,1 fully in flight; wait tile 0 (newest 4 = tile 1)
  stageA(0); stageB(0);
  stageA(1); stageB(1);
  asm volatile("s_waitcnt vmcnt(4)" ::: "memory");
  __builtin_amdgcn_s_barrier();

  for (int T = 0; T < NTILES; ++T) {
    const int s = T & 3;
    const unsigned short* sAs = &sA[s * SLOT_SH];
    const unsigned short* sBs = &sB[s * SLOT_SH];

    // issue next-next tile's loads first (depth-2 prefetch; slot free since T-2)
    if (T < NTILES - 2) { stageA(T + 2); stageB(T + 2); }

    // LDS -> register fragments (compiler inserts fine-grained lgkmcnt)
    short8 af[8], bf[4];
    #pragma unroll
    for (int i = 0; i < 8; ++i)
      af[i] = *(const short8*)&sAs[(wm * 128 + i * 16 + mrow) * 32 + rs];
    #pragma unroll
    for (int j = 0; j < 4; ++j)
      bf[j] = *(const short8*)&sBs[(wn * 64 + j * 16 + mrow) * 32 + rs];

    __builtin_amdgcn_s_setprio(1);
    #pragma unroll
    for (int i = 0; i < 8; ++i)
      #pragma unroll
      for (int j = 0; j < 4; ++j)
        acc[i][j] = __builtin_amdgcn_mfma_f32_16x16x32_bf16(af[i], bf[j], acc[i][j], 0, 0, 0);
    __builtin_amdgcn_s_setprio(0);

    if (T < NTILES - 1) {
      // counted wait: tile T+1 guaranteed landed, tile T+2 stays in flight
      if (T < NTILES - 2) asm volatile("s_waitcnt vmcnt(4)" ::: "memory");
      else                asm volatile("s_waitcnt vmcnt(0)" ::: "memory");
      __builtin_amdgcn_s_barrier();

      // expert boundary: fold gate weight via in-place rescale (telescoping)
      if ((T & 127) == 127) {
        const int e = T >> 7;
        #pragma unroll
        for (int i = 0; i < 8; ++i) {
          #pragma unroll
          for (int r = 0; r < 4; ++r) {
            const int row_l = wm * 128 + i * 16 + quad * 4 + r;
            const float sc = sG[row_l * 8 + e] / sG[row_l * 8 + e + 1];
            #pragma unroll
            for (int j = 0; j < 4; ++j) acc[i][j][r] *= sc;
          }
        }
      }
    }
  }

  // epilogue: *g7, + sum_e g_e * b_e[col]
  #pragma unroll
  for (int i = 0; i < 8; ++i) {
    #pragma unroll
    for (int r = 0; r < 4; ++r) {
      const int row_l = wm * 128 + i * 16 + quad * 4 + r;
      float gv[8];
      #pragma unroll
      for (int e = 0; e < 8; ++e) gv[e] = sG[row_l * 8 + e];
      #pragma unroll
      for (int j = 0; j < 4; ++j) {
        const int col_l = wn * 64 + j * 16 + mrow;
        float bias = 0.f;
        #pragma unroll
        for (int e = 0; e < 8; ++e) bias += gv[e] * sBias[e * 256 + col_l];
        out[(size_t)(row0 + row_l) * DOUT + col0 + col_l] = acc[i][j][r] * gv[7] + bias;
      }
    }
  }
}

// ---------- fallback: fp32, no workspace ----------
__global__ __launch_bounds__(256) void moe_fallback(const float* __restrict__ x,
                                                    const float* __restrict__ gw,
                                                    const float* __restrict__ gb,
                                                    const float* __restrict__ W,
                                                    const float* __restrict__ eb,
                                                    float* __restrict__ out) {
  __shared__ float sX[64][33];
  __shared__ float sW[32][65];
  __shared__ float sLog[64][8];
  __shared__ float sGate[64][8];
  const int t = threadIdx.x;
  const int r0 = blockIdx.y * 64, c0 = blockIdx.x * 64;

  const int grow = t & 63, epair = t >> 6;
  float lg0 = gb[2 * epair], lg1 = gb[2 * epair + 1];
  for (int d0 = 0; d0 < DIN; d0 += 32) {
    for (int i = 0; i < 8; ++i) {
      int lin = i * 256 + t, rr = lin >> 5, cc = lin & 31;
      sX[rr][cc] = x[(size_t)(r0 + rr) * DIN + d0 + cc];
    }
    __syncthreads();
    for (int dd = 0; dd < 32; ++dd) {
      float xv = sX[grow][dd];
      lg0 += xv * gw[(size_t)(d0 + dd) * 8 + 2 * epair];
      lg1 += xv * gw[(size_t)(d0 + dd) * 8 + 2 * epair + 1];
    }
    __syncthreads();
  }
  sLog[grow][2 * epair] = lg0;
  sLog[grow][2 * epair + 1] = lg1;
  __syncthreads();
  if (t < 64) {
    float m = -1e30f, s = 0.f, ex[8];
    for (int e = 0; e < 8; ++e) m = fmaxf(m, sLog[t][e]);
    for (int e = 0; e < 8; ++e) { ex[e] = expf(sLog[t][e] - m); s += ex[e]; }
    for (int e = 0; e < 8; ++e) sGate[t][e] = ex[e] / s;
  }
  __syncthreads();

  const int tr = t >> 4, tc = t & 15;
  float acc[4][4] = {};
  for (int e = 0; e < NEXP; ++e) {
    float part[4][4] = {};
    for (int d0 = 0; d0 < DIN; d0 += 32) {
      for (int i = 0; i < 8; ++i) {
        int lin = i * 256 + t, rr = lin >> 5, cc = lin & 31;
        sX[rr][cc] = x[(size_t)(r0 + rr) * DIN + d0 + cc];
      }
      for (int i = 0; i < 8; ++i) {
        int lin = i * 256 + t, dd = lin >> 6, cc = lin & 63;
        sW[dd][cc] = W[(size_t)e * DIN * DOUT + (size_t)(d0 + dd) * DOUT + c0 + cc];
      }
      __syncthreads();
      for (int dd = 0; dd < 32; ++dd) {
        float xa[4], wb[4];
        for (int i = 0; i < 4; ++i) xa[i] = sX[tr + 16 * i][dd];
        for (int j = 0; j < 4; ++j) wb[j] = sW[dd][tc + 16 * j];
        for (int i = 0; i < 4; ++i)
          for (int j = 0; j < 4; ++j) part[i][j] += xa[i] * wb[j];
      }
      __syncthreads();
    }
    for (int i = 0; i < 4; ++i) {
      float g = sGate[tr + 16 * i][e];
      for (int j = 0; j < 4; ++j)
        acc[i][j] += g * (part[i][j] + eb[(size_t)e * DOUT + c0 + tc + 16 * j]);
    }
  }
  for (int i = 0; i < 4; ++i)
    for (int j = 0; j < 4; ++j)
      out[(size_t)(r0 + tr + 16 * i) * DOUT + c0 + tc + 16 * j] = acc[i][j];
}

extern "C" void kernel_launch(void* const* d_in, const int* in_sizes, int n_in,
                              void* d_out, int out_size, void* d_ws, size_t ws_size,
                              hipStream_t stream) {
  const float* x  = (const float*)d_in[0];
  const float* gw = (const float*)d_in[1];
  const float* gb = (const float*)d_in[2];
  const float* W  = (const float*)d_in[3];
  const float* eb = (const float*)d_in[4];
  float* out = (float*)d_out;

  const size_t sz_xb = (size_t)NROWS * DIN * 2;          // 32MB
  const size_t sz_bt = (size_t)DOUT * KTOT * 2;          // 256MB
  const size_t sz_g  = (size_t)NROWS * 8 * 4;            // 128KB
  const size_t need = sz_xb + sz_bt + sz_g;

  if (ws_size >= need) {
    unsigned short* xb = (unsigned short*)d_ws;
    unsigned short* bt = (unsigned short*)((char*)d_ws + sz_xb);
    float* gate = (float*)((char*)d_ws + sz_xb + sz_bt);
    gate_kernel<<<NROWS, 256, 0, stream>>>(x, gw, gb, gate, xb);
    transpose_w<<<dim3(KTOT / 64, DOUT / 256), 256, 0, stream>>>(W, bt);
    gemm_moe<<<(NROWS / BM) * (DOUT / BN), 512, 0, stream>>>(xb, bt, gate, eb, out);
  } else {
    moe_fallback<<<dim3(DOUT / 64, NROWS / 64), 256, 0, stream>>>(x, gw, gb, W, eb, out);
  }
}